// Round 1
// baseline (684.743 us; speedup 1.0000x reference)
//
#include <hip/hip_runtime.h>

// QuantLinear W4A32 — round 7: round-6 + double-buffered DMA pipeline + XCD swizzle.
//  * prep_x / prep_w: unchanged (chunk-indexed, contiguous 16B/lane stores).
//  * qgemm_pre: DMA-fed f16 GEMM, 128x256 tile, 512 threads, BK=32, now with
//    2x LDS buffers: stage(t+1) issued BEFORE compute(t), ONE barrier per K-step
//    (syncthreads' implicit vmcnt(0) drains the staged buffer -> race-free).
//    Bijective XCD-chunk swizzle keeps each 2.56MB W-tile in one XCD's L2.
// Fallbacks by ws_size: round-4 fused-B path, then round-3 fully-fused path.

#define BK 32
#define LDK 40             // padded row stride in halves (80B, 16B-multiple)
#define TILE_BYTES 10240   // A tile: 128 * LDK * 2
#define WTILE_BYTES 20480  // B tile: 256 * LDK * 2

typedef _Float16 v8h __attribute__((ext_vector_type(8)));
typedef _Float16 half2v __attribute__((ext_vector_type(2)));
typedef float v4f __attribute__((ext_vector_type(4)));

__device__ __forceinline__ unsigned pkrtz_u32(float a, float b) {
  return __builtin_bit_cast(unsigned, __builtin_amdgcn_cvt_pkrtz(a, b));
}

__device__ __forceinline__ void load_lds_16B(const void* g, void* l) {
  __builtin_amdgcn_global_load_lds(
      (const __attribute__((address_space(1))) unsigned*)g,
      (__attribute__((address_space(3))) unsigned*)l, 16, 0, 0);
}

// ---------------- prep_x: fp32 -> f16 tiled-padded, coalesced stores ----------
// grid (K/32, M/128), 320 threads; 640 16B-chunks per tile, 2 per thread.
// chunk c -> row r=c/5, slot j=c%5 (j==4 is padding).
__global__ __launch_bounds__(320)
void prep_x(const float* __restrict__ x, unsigned short* __restrict__ xt, int K) {
  const int kt = blockIdx.x, mt = blockIdx.y;
  unsigned short* tile = xt + (size_t)(mt * (K / 32) + kt) * (TILE_BYTES / 2);
#pragma unroll
  for (int p = 0; p < 2; ++p) {
    const int c = threadIdx.x + p * 320;
    const int r = c / 5, j = c - r * 5;
    uint4 o = {0u, 0u, 0u, 0u};
    if (j < 4) {
      const float* src = x + (size_t)(mt * 128 + r) * K + kt * 32 + j * 8;
      const float4 v0 = ((const float4*)src)[0];
      const float4 v1 = ((const float4*)src)[1];
      o.x = pkrtz_u32(v0.x, v0.y); o.y = pkrtz_u32(v0.z, v0.w);
      o.z = pkrtz_u32(v1.x, v1.y); o.w = pkrtz_u32(v1.z, v1.w);
    }
    *(uint4*)((char*)tile + (size_t)c * 16) = o;  // coalesced
  }
}

// ---------------- prep_w: 4-bit -> f16 tiled-padded, coalesced stores --------
// grid (N/256, K/32), 256 threads; 1280 chunks per tile, 5 per thread.
// chunk c -> col n=c/5, slot j=c%5; one qweight word -> one 16B chunk.
__global__ __launch_bounds__(256)
void prep_w(const unsigned* __restrict__ qweight,
            const unsigned* __restrict__ qzeros,
            const float* __restrict__ scales,
            unsigned short* __restrict__ wt, int N, int K) {
  const int nt = blockIdx.x, kt = blockIdx.y;
  const int g = kt >> 2;
  unsigned short* tile = wt + (size_t)(nt * (K / 32) + kt) * (WTILE_BYTES / 2);
#pragma unroll
  for (int p = 0; p < 5; ++p) {
    const int c = threadIdx.x + p * 256;
    const int n = c / 5, j = c - n * 5;
    const int gn = nt * 256 + n;
    uint4 o = {0u, 0u, 0u, 0u};
    if (j < 4) {
      const unsigned zp = qzeros[(size_t)g * (N >> 3) + (gn >> 3)];
      const float s = scales[(size_t)g * N + gn];
      const unsigned z = (zp >> ((gn & 7) * 4)) & 15u;
      const unsigned hz_u = 0x64006400u | z | (z << 16);
      const half2v hz2 = __builtin_bit_cast(half2v, hz_u);
      const half2v hs2 = __builtin_bit_cast(half2v, pkrtz_u32(s, s));
      const unsigned qv = qweight[(size_t)(kt * 4 + j) * N + gn];
      unsigned* wp = (unsigned*)&o;
#pragma unroll
      for (int b = 0; b < 4; ++b) {
        const unsigned byte = qv >> (8 * b);
        const unsigned pq = 0x64006400u | (byte & 0xFu) | ((byte & 0xF0u) << 12);
        const half2v w2 = (__builtin_bit_cast(half2v, pq) - hz2) * hs2;
        wp[b] = __builtin_bit_cast(unsigned, w2);
      }
    }
    *(uint4*)((char*)tile + (size_t)c * 16) = o;  // coalesced
  }
}

// ---------------- main: DMA GEMM, 128x256 tile, double-buffered pipeline -----
__global__ __launch_bounds__(512, 4)
void qgemm_pre(const unsigned short* __restrict__ xt,
               const unsigned short* __restrict__ wt,
               float* __restrict__ out, int M, int N, int K) {
  __shared__ __align__(16) short As[2][128][LDK];
  __shared__ __align__(16) short Bs[2][256][LDK];

  const int tid = threadIdx.x;
  const int lane = tid & 63;
  const int wid = tid >> 6;  // 8 waves

  // Bijective XCD-chunk swizzle: consecutive dispatch ids round-robin XCDs;
  // give each XCD a contiguous chunk of the m-fastest order so its resident
  // blocks share W n-columns out of its own 4MB L2 (not just L3).
  const int gx = gridDim.x;
  const int nwg = gx * gridDim.y;
  int bid = blockIdx.x + gx * blockIdx.y;
  {
    const int xcd = bid & 7;
    const int idx = bid >> 3;
    const int q = nwg >> 3, r = nwg & 7;
    bid = (xcd < r ? xcd * (q + 1) : r * (q + 1) + (xcd - r) * q) + idx;
  }
  const int mt = bid % gx;       // m-tiles fastest (W L2 reuse within XCD)
  const int nt = bid / gx;
  const int n0 = nt * 256, m0 = mt * 128;
  const int wm = (wid >> 2) * 64;
  const int wn = (wid & 3) * 64;
  const int lr = lane & 15;
  const int lk = (lane >> 4) * 8;

  const int NT = K / BK;  // 128
  const char* ga0 = (const char*)xt + (size_t)mt * NT * TILE_BYTES +
                    wid * 1024 + lane * 16;
  const char* gb0 = (const char*)wt + (size_t)nt * NT * WTILE_BYTES +
                    wid * 1024 + lane * 16;

  v4f acc[4][4] = {};

  // ---- stage tile t into buffer b (issue-only; drained by syncthreads) ----
  auto stage = [&](int b, int t) {
    const char* ga = ga0 + (size_t)t * TILE_BYTES;
    const char* gb = gb0 + (size_t)t * WTILE_BYTES;
    char* la = ((char*)&As[b][0][0]) + wid * 1024;  // HW adds lane*16
    char* lb = ((char*)&Bs[b][0][0]) + wid * 1024;
    load_lds_16B(ga, la);                                        // A: 8KB
    if (wid < 2) load_lds_16B(ga + 8 * 1024, la + 8 * 1024);     // A: +2KB
    load_lds_16B(gb, lb);                                        // B: 8KB
    load_lds_16B(gb + 8 * 1024, lb + 8 * 1024);                  // B: +8KB
    if (wid < 4) load_lds_16B(gb + 16 * 1024, lb + 16 * 1024);   // B: +4KB
  };

  // ---- compute one K-step from buffer b ----
  auto compute = [&](int b) {
    v8h af[4], bfr[4];
#pragma unroll
    for (int i = 0; i < 4; ++i) {
      af[i] = *(const v8h*)(&As[b][wm + i * 16 + lr][lk]);   // ds_read_b128
      bfr[i] = *(const v8h*)(&Bs[b][wn + i * 16 + lr][lk]);  // ds_read_b128
    }
    __builtin_amdgcn_s_setprio(1);
#pragma unroll
    for (int mi = 0; mi < 4; ++mi) {
#pragma unroll
      for (int ni = 0; ni < 4; ++ni) {
        acc[mi][ni] = __builtin_amdgcn_mfma_f32_16x16x32_f16(
            af[mi], bfr[ni], acc[mi][ni], 0, 0, 0);
      }
    }
    __builtin_amdgcn_s_setprio(0);
  };

  // prologue
  stage(0, 0);
  __syncthreads();  // implicit vmcnt(0) drain -> buf0 valid

  // steady state: stage(t+1) overlaps compute(t); ONE barrier per K-step.
  // Hazards: buf b^1 was last READ at iter t-1 (barrier passed); buf b was
  // STAGED at iter t-1 (barrier's vmcnt(0) drained it). Both safe.
#pragma unroll 2
  for (int t = 0; t < NT - 1; ++t) {
    const int b = t & 1;
    stage(b ^ 1, t + 1);
    compute(b);
    __syncthreads();
  }
  compute((NT - 1) & 1);  // last tile, no barrier needed

  // ---- epilogue: C/D layout col=lane&15, row=(lane>>4)*4+reg ----
#pragma unroll
  for (int mi = 0; mi < 4; ++mi) {
#pragma unroll
    for (int ni = 0; ni < 4; ++ni) {
#pragma unroll
      for (int r = 0; r < 4; ++r) {
        const int row = m0 + wm + mi * 16 + (lane >> 4) * 4 + r;
        const int col = n0 + wn + ni * 16 + lr;
        out[(size_t)row * N + col] = acc[mi][ni][r];
      }
    }
  }
}

// ---------------- fallback 1: round-4 (A DMA, B fused dequant) ----------------
__global__ __launch_bounds__(512, 4)
void qgemm_dma(const unsigned short* __restrict__ xt,
               const unsigned* __restrict__ qweight,
               const unsigned* __restrict__ qzeros,
               const float* __restrict__ scales,
               float* __restrict__ out, int M, int N, int K) {
  __shared__ __align__(16) short As[128][LDK];
  __shared__ __align__(16) short Bs[256][LDK];

  const int tid = threadIdx.x;
  const int lane = tid & 63;
  const int wid = tid >> 6;
  const int n0 = blockIdx.x * 256;
  const int m0 = blockIdx.y * 128;
  const int mt = blockIdx.y;
  const int wm = (wid >> 2) * 64;
  const int wn = (wid & 3) * 64;
  const int lr = lane & 15;
  const int lk = (lane >> 4) * 8;

  const int b_n = tid & 255;
  const int b_kr0 = tid >> 8;
  const int gn = n0 + b_n;
  const unsigned* qwb = qweight + (size_t)b_kr0 * N + gn;

  const char* xt_b = (const char*)xt;
  const int NT = K / BK;

  v4f acc[4][4] = {};

  unsigned b0c, b1c, zpc;
  float scc;
  auto load_b = [&](int t, unsigned& b0, unsigned& b1, unsigned& zp, float& sc) {
    const int kk = t * BK;
    const size_t qoff = (size_t)(kk >> 3) * N;
    b0 = qwb[qoff];
    b1 = qwb[qoff + 2 * (size_t)N];
    const int g = kk >> 7;
    zp = qzeros[(size_t)g * (N >> 3) + (gn >> 3)];
    sc = scales[(size_t)g * N + gn];
  };
  load_b(0, b0c, b1c, zpc, scc);

#pragma unroll 2
  for (int t = 0; t < NT; ++t) {
    {
      const char* g = xt_b + (size_t)(mt * NT + t) * TILE_BYTES +
                      (size_t)wid * 1024 + (size_t)lane * 16;
      char* l = ((char*)&As[0][0]) + wid * 1024;
      load_lds_16B(g, l);
      if (wid < 2) load_lds_16B(g + 8 * 1024, l + 8 * 1024);
    }
    {
      const unsigned z = (zpc >> ((gn & 7) * 4)) & 15u;
      const unsigned hz_u = 0x64006400u | z | (z << 16);
      const half2v hz2 = __builtin_bit_cast(half2v, hz_u);
      const half2v hs2 = __builtin_bit_cast(half2v, pkrtz_u32(scc, scc));
      const unsigned qvs[2] = {b0c, b1c};
#pragma unroll
      for (int q = 0; q < 2; ++q) {
        const int kr = b_kr0 + q * 2;
        const unsigned qv = qvs[q];
        uint4 wv;
        unsigned* wp = (unsigned*)&wv;
#pragma unroll
        for (int j = 0; j < 4; ++j) {
          const unsigned byte = qv >> (8 * j);
          const unsigned pq = 0x64006400u | (byte & 0xFu) | ((byte & 0xF0u) << 12);
          const half2v w2 = (__builtin_bit_cast(half2v, pq) - hz2) * hs2;
          wp[j] = __builtin_bit_cast(unsigned, w2);
        }
        *(uint4*)(&Bs[b_n][kr * 8]) = wv;
      }
    }

    __syncthreads();

    unsigned b0n, b1n, zpn;
    float scn;
    const int tn = (t + 1 < NT) ? (t + 1) : t;
    load_b(tn, b0n, b1n, zpn, scn);

    v8h af[4], bfr[4];
#pragma unroll
    for (int i = 0; i < 4; ++i) {
      af[i] = *(const v8h*)(&As[wm + i * 16 + lr][lk]);
      bfr[i] = *(const v8h*)(&Bs[wn + i * 16 + lr][lk]);
    }
#pragma unroll
    for (int mi = 0; mi < 4; ++mi) {
#pragma unroll
      for (int ni = 0; ni < 4; ++ni) {
        acc[mi][ni] = __builtin_amdgcn_mfma_f32_16x16x32_f16(
            af[mi], bfr[ni], acc[mi][ni], 0, 0, 0);
      }
    }

    __syncthreads();

    b0c = b0n; b1c = b1n; zpc = zpn; scc = scn;
  }

#pragma unroll
  for (int mi = 0; mi < 4; ++mi) {
#pragma unroll
    for (int ni = 0; ni < 4; ++ni) {
#pragma unroll
      for (int r = 0; r < 4; ++r) {
        const int row = m0 + wm + mi * 16 + (lane >> 4) * 4 + r;
        const int col = n0 + wn + ni * 16 + lr;
        out[(size_t)row * N + col] = acc[mi][ni][r];
      }
    }
  }
}

// ---------------- fallback 2: round-3 fully fused (128x128) ----------------
__global__ __launch_bounds__(256, 2)
void qgemm_fused(const float* __restrict__ x,
                 const unsigned* __restrict__ qweight,
                 const unsigned* __restrict__ qzeros,
                 const float* __restrict__ scales,
                 float* __restrict__ out, int M, int N, int K) {
  __shared__ short As[128][LDK];
  __shared__ short Bs[128][LDK];

  const int tid = threadIdx.x;
  const int lane = tid & 63;
  const int wid = tid >> 6;
  const int n0 = blockIdx.x * 128;
  const int m0 = blockIdx.y * 128;
  const int wm = (wid >> 1) * 64;
  const int wn = (wid & 1) * 64;
  const int lr = lane & 15;
  const int lk = (lane >> 4) * 8;

  const int a_row = tid >> 3;
  const int a_col = (tid & 7) * 4;
  const int b_n = tid & 127;
  const int b_kr0 = tid >> 7;
  const int gn = n0 + b_n;

  const float* xb = x + (size_t)(m0 + a_row) * K + a_col;
  const unsigned* qwb = qweight + (size_t)b_kr0 * N + gn;

  v4f acc[4][4] = {};
  const int NT = K / BK;

  float4 axc[4];
  unsigned b0c, b1c, zpc;
  float scc;

  auto load_step = [&](int t, float4 ax[4], unsigned& b0, unsigned& b1,
                       unsigned& zp, float& sc) {
    const int kk = t * BK;
#pragma unroll
    for (int p = 0; p < 4; ++p)
      ax[p] = *(const float4*)(xb + (size_t)(p * 32) * K + kk);
    const size_t qoff = (size_t)(kk >> 3) * N;
    b0 = qwb[qoff];
    b1 = qwb[qoff + 2 * (size_t)N];
    const int g = kk >> 7;
    zp = qzeros[(size_t)g * (N >> 3) + (gn >> 3)];
    sc = scales[(size_t)g * N + gn];
  };

  load_step(0, axc, b0c, b1c, zpc, scc);

#pragma unroll 2
  for (int t = 0; t < NT; ++t) {
    const unsigned z = (zpc >> ((gn & 7) * 4)) & 15u;
    const unsigned hz_u = 0x64006400u | z | (z << 16);
    const half2v hz2 = __builtin_bit_cast(half2v, hz_u);
    const half2v hs2 = __builtin_bit_cast(half2v, pkrtz_u32(scc, scc));

#pragma unroll
    for (int p = 0; p < 4; ++p) {
      const int row = p * 32 + a_row;
      uint2 pv;
      pv.x = pkrtz_u32(axc[p].x, axc[p].y);
      pv.y = pkrtz_u32(axc[p].z, axc[p].w);
      *(uint2*)(&As[row][a_col]) = pv;
    }
    {
      const unsigned qvs[2] = {b0c, b1c};
#pragma unroll
      for (int q = 0; q < 2; ++q) {
        const int kr = b_kr0 + q * 2;
        const unsigned qv = qvs[q];
        uint4 wv;
        unsigned* wp = (unsigned*)&wv;
#pragma unroll
        for (int j = 0; j < 4; ++j) {
          const unsigned byte = qv >> (8 * j);
          const unsigned pq = 0x64006400u | (byte & 0xFu) | ((byte & 0xF0u) << 12);
          const half2v w2 = (__builtin_bit_cast(half2v, pq) - hz2) * hs2;
          wp[j] = __builtin_bit_cast(unsigned, w2);
        }
        *(uint4*)(&Bs[b_n][kr * 8]) = wv;
      }
    }

    __syncthreads();

    float4 axn[4];
    unsigned b0n, b1n, zpn;
    float scn;
    const int tn = (t + 1 < NT) ? (t + 1) : t;
    load_step(tn, axn, b0n, b1n, zpn, scn);

    v8h af[4], bfr[4];
#pragma unroll
    for (int i = 0; i < 4; ++i) {
      af[i] = *(const v8h*)(&As[wm + i * 16 + lr][lk]);
      bfr[i] = *(const v8h*)(&Bs[wn + i * 16 + lr][lk]);
    }
#pragma unroll
    for (int mi = 0; mi < 4; ++mi) {
#pragma unroll
      for (int ni = 0; ni < 4; ++ni) {
        acc[mi][ni] = __builtin_amdgcn_mfma_f32_16x16x32_f16(
            af[mi], bfr[ni], acc[mi][ni], 0, 0, 0);
      }
    }

    __syncthreads();

#pragma unroll
    for (int p = 0; p < 4; ++p) axc[p] = axn[p];
    b0c = b0n; b1c = b1n; zpc = zpn; scc = scn;
  }

#pragma unroll
  for (int mi = 0; mi < 4; ++mi) {
#pragma unroll
    for (int ni = 0; ni < 4; ++ni) {
#pragma unroll
      for (int r = 0; r < 4; ++r) {
        const int row = m0 + wm + mi * 16 + (lane >> 4) * 4 + r;
        const int col = n0 + wn + ni * 16 + lr;
        out[(size_t)row * N + col] = acc[mi][ni][r];
      }
    }
  }
}

extern "C" void kernel_launch(void* const* d_in, const int* in_sizes, int n_in,
                              void* d_out, int out_size, void* d_ws, size_t ws_size,
                              hipStream_t stream) {
  const float* x = (const float*)d_in[0];
  const unsigned* qweight = (const unsigned*)d_in[1];
  const unsigned* qzeros = (const unsigned*)d_in[2];
  const float* scales = (const float*)d_in[3];
  float* out = (float*)d_out;

  const int K = 4096;
  const int N = 11008;
  const int M = in_sizes[0] / K;  // 4096

  const size_t A_BYTES = (size_t)(M / 128) * (K / 32) * TILE_BYTES;   // 41.9 MB
  const size_t W_BYTES = (size_t)(N / 256) * (K / 32) * WTILE_BYTES;  // 112.7 MB

  if (ws_size >= A_BYTES + W_BYTES) {
    unsigned short* xt = (unsigned short*)d_ws;
    unsigned short* wtp = (unsigned short*)((char*)d_ws + A_BYTES);
    prep_x<<<dim3(K / 32, M / 128), 320, 0, stream>>>(x, xt, K);
    prep_w<<<dim3(N / 256, K / 32), 256, 0, stream>>>(qweight, qzeros, scales, wtp, N, K);
    qgemm_pre<<<dim3(M / 128, N / 256), 512, 0, stream>>>(xt, wtp, out, M, N, K);
  } else if (ws_size >= A_BYTES) {
    unsigned short* xt = (unsigned short*)d_ws;
    prep_x<<<dim3(K / 32, M / 128), 320, 0, stream>>>(x, xt, K);
    qgemm_dma<<<dim3(N / 256, M / 128), 512, 0, stream>>>(xt, qweight, qzeros, scales,
                                                          out, M, N, K);
  } else {
    qgemm_fused<<<dim3(N / 128, M / 128), 256, 0, stream>>>(x, qweight, qzeros, scales,
                                                            out, M, N, K);
  }
}

// Round 2
// 622.104 us; speedup vs baseline: 1.1007x; 1.1007x over previous
//
#include <hip/hip_runtime.h>

// QuantLinear W4A32 — round 8: 8-phase 256x256 deep-pipelined DMA GEMM (T2+T3+T4+T5).
//  * prep_a8 / prep_b8: write unpadded 32KB K-tiles (256 rows x 64 k of f16),
//    PRE-SWIZZLED (16B slot ^= row&7 within each 128B row) so the GEMM stages with
//    linear global_load_lds and reads conflict-free via the matching XOR (rule #21).
//  * qgemm8: BM=BN=256, BK=64, 512 thr / 8 waves (2x4), per-wave 128x64 output.
//    8 phases per 2 K-tiles: {ds_read frags; stage 1 half-tile (2 loads/thread);
//    [vmcnt(4) at P4/P8]; s_barrier; setprio(1); 16 MFMA; setprio(0); s_barrier}.
//    Counted vmcnt keeps 2 half-tiles in flight across barriers (no vmcnt(0) drain).
//    Buffer hazard windows: each LDS region's overwrite-issue slot is barrier-after
//    its last read phase (A read P1/P3 -> issued P5/P6|P1/P2; B read P1/P2 -> P3/P4|P7/P8).
// Fallbacks by ws_size: round-4 A-DMA path, then round-3 fully-fused path.

#define BK 32
#define LDK 40             // legacy padded row stride (fallback path)
#define TILE_BYTES 10240   // legacy A tile

typedef _Float16 v8h __attribute__((ext_vector_type(8)));
typedef _Float16 half2v __attribute__((ext_vector_type(2)));
typedef float v4f __attribute__((ext_vector_type(4)));

__device__ __forceinline__ unsigned pkrtz_u32(float a, float b) {
  return __builtin_bit_cast(unsigned, __builtin_amdgcn_cvt_pkrtz(a, b));
}

__device__ __forceinline__ void load_lds_16B(const void* g, void* l) {
  __builtin_amdgcn_global_load_lds(
      (const __attribute__((address_space(1))) unsigned*)g,
      (__attribute__((address_space(3))) unsigned*)l, 16, 0, 0);
}

__device__ __forceinline__ void bar() { asm volatile("s_barrier" ::: "memory"); }

// ---------------- prep_a8: fp32 -> f16 swizzled K-tiles ----------------------
// grid (K/64, M/256), 512 threads; 2048 16B-chunks per 32KB tile, 4 per thread.
// chunk c: h=c>>10 (128-row half), r=(c>>3)&127, s=c&7 (16B slot = 8 k-values).
// store slot at s^(r&7) -> conflict-free swizzled reads in qgemm8.
__global__ __launch_bounds__(512)
void prep_a8(const float* __restrict__ x, unsigned short* __restrict__ fa, int K) {
  const int t = blockIdx.x, mt = blockIdx.y;
  unsigned short* tile = fa + (size_t)(mt * (K / 64) + t) * 16384;
#pragma unroll
  for (int p = 0; p < 4; ++p) {
    const int c = threadIdx.x + p * 512;
    const int h = c >> 10, r = (c >> 3) & 127, s = c & 7;
    const float* src = x + (size_t)(mt * 256 + h * 128 + r) * K + t * 64 + s * 8;
    const float4 v0 = ((const float4*)src)[0];
    const float4 v1 = ((const float4*)src)[1];
    uint4 o;
    o.x = pkrtz_u32(v0.x, v0.y); o.y = pkrtz_u32(v0.z, v0.w);
    o.z = pkrtz_u32(v1.x, v1.y); o.w = pkrtz_u32(v1.z, v1.w);
    *(uint4*)(tile + h * 8192 + r * 64 + ((s ^ (r & 7)) << 3)) = o;
  }
}

// ---------------- prep_b8: 4-bit -> f16 swizzled K-tiles ---------------------
// grid (N/256, K/64), 512 threads; one qweight word -> one 16B chunk (8 k of col n).
__global__ __launch_bounds__(512)
void prep_b8(const unsigned* __restrict__ qweight,
             const unsigned* __restrict__ qzeros,
             const float* __restrict__ scales,
             unsigned short* __restrict__ fb, int N, int K) {
  const int nt = blockIdx.x, t = blockIdx.y;
  const int g = t >> 1;  // GROUP=128 = 2 K-tiles
  unsigned short* tile = fb + (size_t)(nt * (K / 64) + t) * 16384;
#pragma unroll
  for (int p = 0; p < 4; ++p) {
    const int c = threadIdx.x + p * 512;
    const int h = c >> 10, r = (c >> 3) & 127, s = c & 7;
    const int n = nt * 256 + h * 128 + r;
    const unsigned zp = qzeros[(size_t)g * (N >> 3) + (n >> 3)];
    const float sc = scales[(size_t)g * N + n];
    const unsigned z = (zp >> ((n & 7) * 4)) & 15u;
    const unsigned hz_u = 0x64006400u | z | (z << 16);
    const half2v hz2 = __builtin_bit_cast(half2v, hz_u);
    const half2v hs2 = __builtin_bit_cast(half2v, pkrtz_u32(sc, sc));
    const unsigned qv = qweight[(size_t)(t * 8 + s) * N + n];
    uint4 o;
    unsigned* wp = (unsigned*)&o;
#pragma unroll
    for (int b = 0; b < 4; ++b) {
      const unsigned byte = qv >> (8 * b);
      const unsigned pq = 0x64006400u | (byte & 0xFu) | ((byte & 0xF0u) << 12);
      const half2v w2 = (__builtin_bit_cast(half2v, pq) - hz2) * hs2;
      wp[b] = __builtin_bit_cast(unsigned, w2);
    }
    *(uint4*)(tile + h * 8192 + r * 64 + ((s ^ (r & 7)) << 3)) = o;
  }
}

// ---------------- main: 8-phase 256x256 pipelined GEMM -----------------------

#define READA4(PA, MB)                                                         \
  _Pragma("unroll") for (int i = 0; i < 4; ++i) {                              \
    aF[i][0] = *(const v8h*)((PA) + ((MB + i) * 16 + lr16) * 128 + koff0);     \
    aF[i][1] = *(const v8h*)((PA) + ((MB + i) * 16 + lr16) * 128 + koff1);     \
  }

#define READB2(PB, BF, NB)                                                     \
  _Pragma("unroll") for (int j = 0; j < 2; ++j) {                              \
    BF[j][0] = *(const v8h*)((PB) + ((NB + j) * 16 + lr16) * 128 + koff0);     \
    BF[j][1] = *(const v8h*)((PB) + ((NB + j) * 16 + lr16) * 128 + koff1);     \
  }

#define MMAQ(MB, NB, BF)                                                       \
  __builtin_amdgcn_s_setprio(1);                                              \
  _Pragma("unroll") for (int i = 0; i < 4; ++i)                                \
  _Pragma("unroll") for (int j = 0; j < 2; ++j) {                              \
    acc[MB + i][NB + j] = __builtin_amdgcn_mfma_f32_16x16x32_f16(              \
        aF[i][0], BF[j][0], acc[MB + i][NB + j], 0, 0, 0);                     \
    acc[MB + i][NB + j] = __builtin_amdgcn_mfma_f32_16x16x32_f16(              \
        aF[i][1], BF[j][1], acc[MB + i][NB + j], 0, 0, 0);                     \
  }                                                                            \
  __builtin_amdgcn_s_setprio(0);

__global__ __launch_bounds__(512, 2)
void qgemm8(const unsigned short* __restrict__ fa,
            const unsigned short* __restrict__ fb,
            float* __restrict__ out, int M, int N, int K) {
  // [dbuf][half 128 rows][row][k] : 2*2*128*64*2B = 64KB each operand
  __shared__ __align__(16) short As[2][2][128][64];
  __shared__ __align__(16) short Bs[2][2][128][64];

  const int tid = threadIdx.x;
  const int lane = tid & 63;
  const int wid = tid >> 6;  // 8 waves: (wr 0..1) x (wc 0..3)
  const int wr = wid >> 2, wc = wid & 3;
  const int lr16 = lane & 15, hi4 = lane >> 4, l7 = lane & 7;
  const int koff0 = ((hi4 ^ l7) << 4);        // ks=0 slot
  const int koff1 = (((4 + hi4) ^ l7) << 4);  // ks=1 slot

  const int nmt = M / 256;            // 16
  const int nwg = nmt * (N / 256);    // 688 (divisible by 8)
  int bid = blockIdx.x;
  {
    const int xcd = bid & 7, idx = bid >> 3;
    const int q = nwg >> 3, r = nwg & 7;
    bid = (xcd < r ? xcd * (q + 1) : r * (q + 1) + (xcd - r) * q) + idx;
  }
  const int mt = bid % nmt;  // m fastest -> W panel L2-resident per XCD
  const int nt = bid / nmt;

  const int NT = K / 64;    // 64 K-tiles
  const int NI = NT / 2;    // 32 iterations (2 K-tiles each)

  // staging: per half-tile each thread DMAs 2x16B at linear offsets c*16, (c+512)*16
  const char* srcA = (const char*)fa + (size_t)mt * NT * 32768 + wid * 1024 + lane * 16;
  const char* srcB = (const char*)fb + (size_t)nt * NT * 32768 + wid * 1024 + lane * 16;
  char* ldsA = (char*)&As[0][0][0][0];
  char* ldsB = (char*)&Bs[0][0][0][0];
  char* dstA = ldsA + wid * 1024;  // HW appends lane*16
  char* dstB = ldsB + wid * 1024;

  auto stageA = [&](int T, int h) {
    const char* s = srcA + (size_t)T * 32768 + h * 16384;
    char* d = dstA + (T & 1) * 32768 + h * 16384;
    load_lds_16B(s, d);
    load_lds_16B(s + 8192, d + 8192);
  };
  auto stageB = [&](int T, int h) {
    const char* s = srcB + (size_t)T * 32768 + h * 16384;
    char* d = dstB + (T & 1) * 32768 + h * 16384;
    load_lds_16B(s, d);
    load_lds_16B(s + 8192, d + 8192);
  };

  // frag-read base pointers per dbuf (wave-fixed half selection)
  const char* pA[2] = {ldsA + wr * 16384, ldsA + 32768 + wr * 16384};
  const char* pB[2] = {ldsB + (wc >> 1) * 16384 + (wc & 1) * 8192,
                       ldsB + 32768 + (wc >> 1) * 16384 + (wc & 1) * 8192};

  v4f acc[8][4] = {};
  v8h aF[4][2], bL[2][2], bH[2][2];

  // ---- prologue: t0 {B0,B1,A0,A1}, t1 {B0,B1}; wait all t0 (4 = t1-B in flight)
  stageB(0, 0); stageB(0, 1); stageA(0, 0); stageA(0, 1);
  stageB(1, 0); stageB(1, 1);
  asm volatile("s_waitcnt vmcnt(4)");
  bar();

  for (int it = 0; it < NI; ++it) {
    const int t0 = 2 * it, t1 = 2 * it + 1;
    const bool pf = (it < NI - 1);

    // ======== K-tile t0 (dbuf 0) ========
    // P1: aLo + bL ; stage A(t1,h0) -> dbuf1 (its prev occupant read ended last iter)
    READA4(pA[0], 0);
    READB2(pA[0] == nullptr ? pB[0] : pB[0], bL, 0);  // (plain read; see below)
    stageA(t1, 0);
    bar();
    MMAQ(0, 0, bL);
    bar();
    // P2: bH ; stage A(t1,h1)
    READB2(pB[0], bH, 2);
    stageA(t1, 1);
    bar();
    MMAQ(0, 2, bH);
    bar();
    // P3: aHi ; stage B(t0+2,h0) -> dbuf0-B (B reads of t0 ended at P2)
    READA4(pA[0], 4);
    if (pf) stageB(t0 + 2, 0);
    bar();
    MMAQ(4, 0, bL);
    bar();
    // P4: stage B(t0+2,h1) ; counted wait: t1 fully landed, only t2-B (4) in flight
    if (pf) { stageB(t0 + 2, 1); asm volatile("s_waitcnt vmcnt(4)"); }
    else    { asm volatile("s_waitcnt vmcnt(0)"); }
    bar();
    MMAQ(4, 2, bH);
    bar();

    // ======== K-tile t1 (dbuf 1) ========
    // P5: aLo + bL ; stage A(t0+2,h0) -> dbuf0-A (A reads of t0 ended at P3)
    READA4(pA[1], 0);
    READB2(pB[1], bL, 0);
    if (pf) stageA(t0 + 2, 0);
    bar();
    MMAQ(0, 0, bL);
    bar();
    // P6: bH ; stage A(t0+2,h1)
    READB2(pB[1], bH, 2);
    if (pf) stageA(t0 + 2, 1);
    bar();
    MMAQ(0, 2, bH);
    bar();
    // P7: aHi ; stage B(t1+2,h0) -> dbuf1-B (B reads of t1 ended at P6)
    READA4(pA[1], 4);
    if (pf) stageB(t1 + 2, 0);
    bar();
    MMAQ(4, 0, bL);
    bar();
    // P8: stage B(t1+2,h1) ; counted wait: t2 fully landed, only t3-B (4) in flight
    if (pf) { stageB(t1 + 2, 1); asm volatile("s_waitcnt vmcnt(4)"); }
    else    { asm volatile("s_waitcnt vmcnt(0)"); }
    bar();
    MMAQ(4, 2, bH);
    bar();
  }

  // ---- epilogue: C/D layout col=lane&15, row=(lane>>4)*4+reg (verified) ----
  const int m0 = mt * 256 + wr * 128;
  const int n0 = nt * 256 + wc * 64;
#pragma unroll
  for (int mi = 0; mi < 8; ++mi) {
#pragma unroll
    for (int ni = 0; ni < 4; ++ni) {
#pragma unroll
      for (int r = 0; r < 4; ++r) {
        const int row = m0 + mi * 16 + hi4 * 4 + r;
        const int col = n0 + ni * 16 + lr16;
        out[(size_t)row * N + col] = acc[mi][ni][r];
      }
    }
  }
}

// ---------------- legacy prep_x (fallback path) ------------------------------
__global__ __launch_bounds__(320)
void prep_x(const float* __restrict__ x, unsigned short* __restrict__ xt, int K) {
  const int kt = blockIdx.x, mt = blockIdx.y;
  unsigned short* tile = xt + (size_t)(mt * (K / 32) + kt) * (TILE_BYTES / 2);
#pragma unroll
  for (int p = 0; p < 2; ++p) {
    const int c = threadIdx.x + p * 320;
    const int r = c / 5, j = c - r * 5;
    uint4 o = {0u, 0u, 0u, 0u};
    if (j < 4) {
      const float* src = x + (size_t)(mt * 128 + r) * K + kt * 32 + j * 8;
      const float4 v0 = ((const float4*)src)[0];
      const float4 v1 = ((const float4*)src)[1];
      o.x = pkrtz_u32(v0.x, v0.y); o.y = pkrtz_u32(v0.z, v0.w);
      o.z = pkrtz_u32(v1.x, v1.y); o.w = pkrtz_u32(v1.z, v1.w);
    }
    *(uint4*)((char*)tile + (size_t)c * 16) = o;
  }
}

// ---------------- fallback 1: round-4 (A DMA, B fused dequant) ----------------
__global__ __launch_bounds__(512, 4)
void qgemm_dma(const unsigned short* __restrict__ xt,
               const unsigned* __restrict__ qweight,
               const unsigned* __restrict__ qzeros,
               const float* __restrict__ scales,
               float* __restrict__ out, int M, int N, int K) {
  __shared__ __align__(16) short As[128][LDK];
  __shared__ __align__(16) short Bs[256][LDK];

  const int tid = threadIdx.x;
  const int lane = tid & 63;
  const int wid = tid >> 6;
  const int n0 = blockIdx.x * 256;
  const int m0 = blockIdx.y * 128;
  const int mt = blockIdx.y;
  const int wm = (wid >> 2) * 64;
  const int wn = (wid & 3) * 64;
  const int lr = lane & 15;
  const int lk = (lane >> 4) * 8;

  const int b_n = tid & 255;
  const int b_kr0 = tid >> 8;
  const int gn = n0 + b_n;
  const unsigned* qwb = qweight + (size_t)b_kr0 * N + gn;

  const char* xt_b = (const char*)xt;
  const int NT = K / BK;

  v4f acc[4][4] = {};

  unsigned b0c, b1c, zpc;
  float scc;
  auto load_b = [&](int t, unsigned& b0, unsigned& b1, unsigned& zp, float& sc) {
    const int kk = t * BK;
    const size_t qoff = (size_t)(kk >> 3) * N;
    b0 = qwb[qoff];
    b1 = qwb[qoff + 2 * (size_t)N];
    const int g = kk >> 7;
    zp = qzeros[(size_t)g * (N >> 3) + (gn >> 3)];
    sc = scales[(size_t)g * N + gn];
  };
  load_b(0, b0c, b1c, zpc, scc);

#pragma unroll 2
  for (int t = 0; t < NT; ++t) {
    {
      const char* g = xt_b + (size_t)(mt * NT + t) * TILE_BYTES +
                      (size_t)wid * 1024 + (size_t)lane * 16;
      char* l = ((char*)&As[0][0]) + wid * 1024;
      load_lds_16B(g, l);
      if (wid < 2) load_lds_16B(g + 8 * 1024, l + 8 * 1024);
    }
    {
      const unsigned z = (zpc >> ((gn & 7) * 4)) & 15u;
      const unsigned hz_u = 0x64006400u | z | (z << 16);
      const half2v hz2 = __builtin_bit_cast(half2v, hz_u);
      const half2v hs2 = __builtin_bit_cast(half2v, pkrtz_u32(scc, scc));
      const unsigned qvs[2] = {b0c, b1c};
#pragma unroll
      for (int q = 0; q < 2; ++q) {
        const int kr = b_kr0 + q * 2;
        const unsigned qv = qvs[q];
        uint4 wv;
        unsigned* wp = (unsigned*)&wv;
#pragma unroll
        for (int j = 0; j < 4; ++j) {
          const unsigned byte = qv >> (8 * j);
          const unsigned pq = 0x64006400u | (byte & 0xFu) | ((byte & 0xF0u) << 12);
          const half2v w2 = (__builtin_bit_cast(half2v, pq) - hz2) * hs2;
          wp[j] = __builtin_bit_cast(unsigned, w2);
        }
        *(uint4*)(&Bs[b_n][kr * 8]) = wv;
      }
    }

    __syncthreads();

    unsigned b0n, b1n, zpn;
    float scn;
    const int tn = (t + 1 < NT) ? (t + 1) : t;
    load_b(tn, b0n, b1n, zpn, scn);

    v8h af[4], bfr[4];
#pragma unroll
    for (int i = 0; i < 4; ++i) {
      af[i] = *(const v8h*)(&As[wm + i * 16 + lr][lk]);
      bfr[i] = *(const v8h*)(&Bs[wn + i * 16 + lr][lk]);
    }
#pragma unroll
    for (int mi = 0; mi < 4; ++mi) {
#pragma unroll
      for (int ni = 0; ni < 4; ++ni) {
        acc[mi][ni] = __builtin_amdgcn_mfma_f32_16x16x32_f16(
            af[mi], bfr[ni], acc[mi][ni], 0, 0, 0);
      }
    }

    __syncthreads();

    b0c = b0n; b1c = b1n; zpc = zpn; scc = scn;
  }

#pragma unroll
  for (int mi = 0; mi < 4; ++mi) {
#pragma unroll
    for (int ni = 0; ni < 4; ++ni) {
#pragma unroll
      for (int r = 0; r < 4; ++r) {
        const int row = m0 + wm + mi * 16 + (lane >> 4) * 4 + r;
        const int col = n0 + wn + ni * 16 + lr;
        out[(size_t)row * N + col] = acc[mi][ni][r];
      }
    }
  }
}

// ---------------- fallback 2: round-3 fully fused (128x128) ----------------
__global__ __launch_bounds__(256, 2)
void qgemm_fused(const float* __restrict__ x,
                 const unsigned* __restrict__ qweight,
                 const unsigned* __restrict__ qzeros,
                 const float* __restrict__ scales,
                 float* __restrict__ out, int M, int N, int K) {
  __shared__ short As[128][LDK];
  __shared__ short Bs[128][LDK];

  const int tid = threadIdx.x;
  const int lane = tid & 63;
  const int wid = tid >> 6;
  const int n0 = blockIdx.x * 128;
  const int m0 = blockIdx.y * 128;
  const int wm = (wid >> 1) * 64;
  const int wn = (wid & 1) * 64;
  const int lr = lane & 15;
  const int lk = (lane >> 4) * 8;

  const int a_row = tid >> 3;
  const int a_col = (tid & 7) * 4;
  const int b_n = tid & 127;
  const int b_kr0 = tid >> 7;
  const int gn = n0 + b_n;

  const float* xb = x + (size_t)(m0 + a_row) * K + a_col;
  const unsigned* qwb = qweight + (size_t)b_kr0 * N + gn;

  v4f acc[4][4] = {};
  const int NT = K / BK;

  float4 axc[4];
  unsigned b0c, b1c, zpc;
  float scc;

  auto load_step = [&](int t, float4 ax[4], unsigned& b0, unsigned& b1,
                       unsigned& zp, float& sc) {
    const int kk = t * BK;
#pragma unroll
    for (int p = 0; p < 4; ++p)
      ax[p] = *(const float4*)(xb + (size_t)(p * 32) * K + kk);
    const size_t qoff = (size_t)(kk >> 3) * N;
    b0 = qwb[qoff];
    b1 = qwb[qoff + 2 * (size_t)N];
    const int g = kk >> 7;
    zp = qzeros[(size_t)g * (N >> 3) + (gn >> 3)];
    sc = scales[(size_t)g * N + gn];
  };

  load_step(0, axc, b0c, b1c, zpc, scc);

#pragma unroll 2
  for (int t = 0; t < NT; ++t) {
    const unsigned z = (zpc >> ((gn & 7) * 4)) & 15u;
    const unsigned hz_u = 0x64006400u | z | (z << 16);
    const half2v hz2 = __builtin_bit_cast(half2v, hz_u);
    const half2v hs2 = __builtin_bit_cast(half2v, pkrtz_u32(scc, scc));

#pragma unroll
    for (int p = 0; p < 4; ++p) {
      const int row = p * 32 + a_row;
      uint2 pv;
      pv.x = pkrtz_u32(axc[p].x, axc[p].y);
      pv.y = pkrtz_u32(axc[p].z, axc[p].w);
      *(uint2*)(&As[row][a_col]) = pv;
    }
    {
      const unsigned qvs[2] = {b0c, b1c};
#pragma unroll
      for (int q = 0; q < 2; ++q) {
        const int kr = b_kr0 + q * 2;
        const unsigned qv = qvs[q];
        uint4 wv;
        unsigned* wp = (unsigned*)&wv;
#pragma unroll
        for (int j = 0; j < 4; ++j) {
          const unsigned byte = qv >> (8 * j);
          const unsigned pq = 0x64006400u | (byte & 0xFu) | ((byte & 0xF0u) << 12);
          const half2v w2 = (__builtin_bit_cast(half2v, pq) - hz2) * hs2;
          wp[j] = __builtin_bit_cast(unsigned, w2);
        }
        *(uint4*)(&Bs[b_n][kr * 8]) = wv;
      }
    }

    __syncthreads();

    float4 axn[4];
    unsigned b0n, b1n, zpn;
    float scn;
    const int tn = (t + 1 < NT) ? (t + 1) : t;
    load_step(tn, axn, b0n, b1n, zpn, scn);

    v8h af[4], bfr[4];
#pragma unroll
    for (int i = 0; i < 4; ++i) {
      af[i] = *(const v8h*)(&As[wm + i * 16 + lr][lk]);
      bfr[i] = *(const v8h*)(&Bs[wn + i * 16 + lr][lk]);
    }
#pragma unroll
    for (int mi = 0; mi < 4; ++mi) {
#pragma unroll
      for (int ni = 0; ni < 4; ++ni) {
        acc[mi][ni] = __builtin_amdgcn_mfma_f32_16x16x32_f16(
            af[mi], bfr[ni], acc[mi][ni], 0, 0, 0);
      }
    }

    __syncthreads();

#pragma unroll
    for (int p = 0; p < 4; ++p) axc[p] = axn[p];
    b0c = b0n; b1c = b1n; zpc = zpn; scc = scn;
  }

#pragma unroll
  for (int mi = 0; mi < 4; ++mi) {
#pragma unroll
    for (int ni = 0; ni < 4; ++ni) {
#pragma unroll
      for (int r = 0; r < 4; ++r) {
        const int row = m0 + wm + mi * 16 + (lane >> 4) * 4 + r;
        const int col = n0 + wn + ni * 16 + lr;
        out[(size_t)row * N + col] = acc[mi][ni][r];
      }
    }
  }
}

extern "C" void kernel_launch(void* const* d_in, const int* in_sizes, int n_in,
                              void* d_out, int out_size, void* d_ws, size_t ws_size,
                              hipStream_t stream) {
  const float* x = (const float*)d_in[0];
  const unsigned* qweight = (const unsigned*)d_in[1];
  const unsigned* qzeros = (const unsigned*)d_in[2];
  const float* scales = (const float*)d_in[3];
  float* out = (float*)d_out;

  const int K = 4096;
  const int N = 11008;
  const int M = in_sizes[0] / K;  // 4096

  const size_t A8 = (size_t)(M / 256) * (K / 64) * 32768;  // 33.6 MB
  const size_t B8 = (size_t)(N / 256) * (K / 64) * 32768;  // 90.2 MB
  const size_t A_BYTES = (size_t)(M / 128) * (K / 32) * TILE_BYTES;  // legacy

  if ((M % 256 == 0) && ws_size >= A8 + B8) {
    unsigned short* fa = (unsigned short*)d_ws;
    unsigned short* fb = (unsigned short*)((char*)d_ws + A8);
    prep_a8<<<dim3(K / 64, M / 256), 512, 0, stream>>>(x, fa, K);
    prep_b8<<<dim3(N / 256, K / 64), 512, 0, stream>>>(qweight, qzeros, scales, fb, N, K);
    qgemm8<<<dim3((M / 256) * (N / 256)), 512, 0, stream>>>(fa, fb, out, M, N, K);
  } else if (ws_size >= A_BYTES) {
    unsigned short* xt = (unsigned short*)d_ws;
    prep_x<<<dim3(K / 32, M / 128), 320, 0, stream>>>(x, xt, K);
    qgemm_dma<<<dim3(N / 256, M / 128), 512, 0, stream>>>(xt, qweight, qzeros, scales,
                                                          out, M, N, K);
  } else {
    qgemm_fused<<<dim3(N / 128, M / 128), 256, 0, stream>>>(x, qweight, qzeros, scales,
                                                            out, M, N, K);
  }
}

// Round 3
// 587.302 us; speedup vs baseline: 1.1659x; 1.0593x over previous
//
#include <hip/hip_runtime.h>

// QuantLinear W4A32 — round 9: 8-phase 256x256 GEMM, ONE barrier per phase.
//  * prep_ab: merged A/B prep (one launch); writes unpadded 32KB K-tiles,
//    pre-swizzled (16B slot ^= row&7) -> linear global_load_lds + conflict-free reads.
//  * qgemm8: per phase {ds_reads; stage; [vmcnt(4) at P4/P8]; s_barrier; MFMA}.
//    Single bar/phase lets waves skew: one wave's ds_read issue overlaps another's
//    MFMA cluster (setprio arbitrates). Overwrite windows re-derived for 1-bar:
//    stage(region) >= last-read-phase + 2 -> B stages consolidated at P4/P8.
//    In-flight ledger (loads/thread): P1+2 P2+2 P4+4(wait->4) P5+2 P6+2 P8+4(wait->4).
// Fallbacks by ws_size: round-4 A-DMA path, then round-3 fully-fused path.

#define BK 32
#define LDK 40             // legacy padded row stride (fallback path)
#define TILE_BYTES 10240   // legacy A tile

typedef _Float16 v8h __attribute__((ext_vector_type(8)));
typedef _Float16 half2v __attribute__((ext_vector_type(2)));
typedef float v4f __attribute__((ext_vector_type(4)));

__device__ __forceinline__ unsigned pkrtz_u32(float a, float b) {
  return __builtin_bit_cast(unsigned, __builtin_amdgcn_cvt_pkrtz(a, b));
}

__device__ __forceinline__ void load_lds_16B(const void* g, void* l) {
  __builtin_amdgcn_global_load_lds(
      (const __attribute__((address_space(1))) unsigned*)g,
      (__attribute__((address_space(3))) unsigned*)l, 16, 0, 0);
}

__device__ __forceinline__ void bar() { asm volatile("s_barrier" ::: "memory"); }

// ---------------- prep_ab: merged operand prep ------------------------------
// A-blocks: fp32 x -> f16 swizzled 32KB K-tiles. B-blocks: 4-bit -> f16 dequant.
// chunk c: h=c>>10 (128-row half), r=(c>>3)&127, s=c&7; store slot s^(r&7).
__global__ __launch_bounds__(512)
void prep_ab(const float* __restrict__ x,
             const unsigned* __restrict__ qweight,
             const unsigned* __restrict__ qzeros,
             const float* __restrict__ scales,
             unsigned short* __restrict__ fa,
             unsigned short* __restrict__ fb, int M, int N, int K) {
  const int KT = K / 64;
  const int NA = (M / 256) * KT;
  int b = blockIdx.x;
  if (b < NA) {
    const int mt = b / KT, t = b - mt * KT;
    unsigned short* tile = fa + (size_t)(mt * KT + t) * 16384;
#pragma unroll
    for (int p = 0; p < 4; ++p) {
      const int c = threadIdx.x + p * 512;
      const int h = c >> 10, r = (c >> 3) & 127, s = c & 7;
      const float* src = x + (size_t)(mt * 256 + h * 128 + r) * K + t * 64 + s * 8;
      const float4 v0 = ((const float4*)src)[0];
      const float4 v1 = ((const float4*)src)[1];
      uint4 o;
      o.x = pkrtz_u32(v0.x, v0.y); o.y = pkrtz_u32(v0.z, v0.w);
      o.z = pkrtz_u32(v1.x, v1.y); o.w = pkrtz_u32(v1.z, v1.w);
      *(uint4*)(tile + h * 8192 + r * 64 + ((s ^ (r & 7)) << 3)) = o;
    }
  } else {
    b -= NA;
    const int nt = b / KT, t = b - nt * KT;
    const int g = t >> 1;  // GROUP=128 = 2 K-tiles
    unsigned short* tile = fb + (size_t)(nt * KT + t) * 16384;
#pragma unroll
    for (int p = 0; p < 4; ++p) {
      const int c = threadIdx.x + p * 512;
      const int h = c >> 10, r = (c >> 3) & 127, s = c & 7;
      const int n = nt * 256 + h * 128 + r;
      const unsigned zp = qzeros[(size_t)g * (N >> 3) + (n >> 3)];
      const float sc = scales[(size_t)g * N + n];
      const unsigned z = (zp >> ((n & 7) * 4)) & 15u;
      const unsigned hz_u = 0x64006400u | z | (z << 16);
      const half2v hz2 = __builtin_bit_cast(half2v, hz_u);
      const half2v hs2 = __builtin_bit_cast(half2v, pkrtz_u32(sc, sc));
      const unsigned qv = qweight[(size_t)(t * 8 + s) * N + n];
      uint4 o;
      unsigned* wp = (unsigned*)&o;
#pragma unroll
      for (int bb = 0; bb < 4; ++bb) {
        const unsigned byte = qv >> (8 * bb);
        const unsigned pq = 0x64006400u | (byte & 0xFu) | ((byte & 0xF0u) << 12);
        const half2v w2 = (__builtin_bit_cast(half2v, pq) - hz2) * hs2;
        wp[bb] = __builtin_bit_cast(unsigned, w2);
      }
      *(uint4*)(tile + h * 8192 + r * 64 + ((s ^ (r & 7)) << 3)) = o;
    }
  }
}

// ---------------- main: 8-phase 256x256 pipelined GEMM, 1 bar/phase ----------

#define READA4(PA, MB)                                                         \
  _Pragma("unroll") for (int i = 0; i < 4; ++i) {                              \
    aF[i][0] = *(const v8h*)((PA) + ((MB + i) * 16 + lr16) * 128 + koff0);     \
    aF[i][1] = *(const v8h*)((PA) + ((MB + i) * 16 + lr16) * 128 + koff1);     \
  }

#define READB2(PB, BF, NB)                                                     \
  _Pragma("unroll") for (int j = 0; j < 2; ++j) {                              \
    BF[j][0] = *(const v8h*)((PB) + ((NB + j) * 16 + lr16) * 128 + koff0);     \
    BF[j][1] = *(const v8h*)((PB) + ((NB + j) * 16 + lr16) * 128 + koff1);     \
  }

#define MMAQ(MB, NB, BF)                                                       \
  __builtin_amdgcn_s_setprio(1);                                              \
  _Pragma("unroll") for (int i = 0; i < 4; ++i)                                \
  _Pragma("unroll") for (int j = 0; j < 2; ++j) {                              \
    acc[MB + i][NB + j] = __builtin_amdgcn_mfma_f32_16x16x32_f16(              \
        aF[i][0], BF[j][0], acc[MB + i][NB + j], 0, 0, 0);                     \
    acc[MB + i][NB + j] = __builtin_amdgcn_mfma_f32_16x16x32_f16(              \
        aF[i][1], BF[j][1], acc[MB + i][NB + j], 0, 0, 0);                     \
  }                                                                            \
  __builtin_amdgcn_s_setprio(0);

__global__ __launch_bounds__(512, 2)
void qgemm8(const unsigned short* __restrict__ fa,
            const unsigned short* __restrict__ fb,
            float* __restrict__ out, int M, int N, int K) {
  // [dbuf][half 128 rows][row][k] : 2*2*128*64*2B = 64KB each operand
  __shared__ __align__(16) short As[2][2][128][64];
  __shared__ __align__(16) short Bs[2][2][128][64];

  const int tid = threadIdx.x;
  const int lane = tid & 63;
  const int wid = tid >> 6;  // 8 waves: (wr 0..1) x (wc 0..3)
  const int wr = wid >> 2, wc = wid & 3;
  const int lr16 = lane & 15, hi4 = lane >> 4, l7 = lane & 7;
  const int koff0 = ((hi4 ^ l7) << 4);        // ks=0 slot
  const int koff1 = (((4 + hi4) ^ l7) << 4);  // ks=1 slot

  const int nmt = M / 256;            // 16
  const int nwg = nmt * (N / 256);    // 688 (divisible by 8)
  int bid = blockIdx.x;
  {
    const int xcd = bid & 7, idx = bid >> 3;
    const int q = nwg >> 3, r = nwg & 7;
    bid = (xcd < r ? xcd * (q + 1) : r * (q + 1) + (xcd - r) * q) + idx;
  }
  const int mt = bid % nmt;  // m fastest -> W panel L2-resident per XCD
  const int nt = bid / nmt;

  const int NT = K / 64;    // 64 K-tiles
  const int NI = NT / 2;    // 32 iterations (2 K-tiles each)

  const char* srcA = (const char*)fa + (size_t)mt * NT * 32768 + wid * 1024 + lane * 16;
  const char* srcB = (const char*)fb + (size_t)nt * NT * 32768 + wid * 1024 + lane * 16;
  char* ldsA = (char*)&As[0][0][0][0];
  char* ldsB = (char*)&Bs[0][0][0][0];
  char* dstA = ldsA + wid * 1024;  // HW appends lane*16
  char* dstB = ldsB + wid * 1024;

  auto stageA = [&](int T, int h) {
    const char* s = srcA + (size_t)T * 32768 + h * 16384;
    char* d = dstA + (T & 1) * 32768 + h * 16384;
    load_lds_16B(s, d);
    load_lds_16B(s + 8192, d + 8192);
  };
  auto stageB = [&](int T, int h) {
    const char* s = srcB + (size_t)T * 32768 + h * 16384;
    char* d = dstB + (T & 1) * 32768 + h * 16384;
    load_lds_16B(s, d);
    load_lds_16B(s + 8192, d + 8192);
  };

  const char* pA[2] = {ldsA + wr * 16384, ldsA + 32768 + wr * 16384};
  const char* pB[2] = {ldsB + (wc >> 1) * 16384 + (wc & 1) * 8192,
                       ldsB + 32768 + (wc >> 1) * 16384 + (wc & 1) * 8192};

  v4f acc[8][4] = {};
  v8h aF[4][2], bL[2][2], bH[2][2];

  // ---- prologue: t0 {B0,B1,A0,A1}, t1 {B0,B1}; wait t0 landed (t1-B in flight)
  stageB(0, 0); stageB(0, 1); stageA(0, 0); stageA(0, 1);
  stageB(1, 0); stageB(1, 1);
  asm volatile("s_waitcnt vmcnt(4)");
  bar();

  for (int it = 0; it < NI; ++it) {
    const int t0 = 2 * it, t1 = 2 * it + 1;
    const bool pf = (it < NI - 1);

    // ======== K-tile t0 (dbuf 0) ========
    // P1: aLo+bL ; stage A(t1,h0) [dbuf1-A last read prev P7 -> P1 = P7+2 OK]
    READA4(pA[0], 0);
    READB2(pB[0], bL, 0);
    stageA(t1, 0);
    bar();
    MMAQ(0, 0, bL);
    // P2: bH ; stage A(t1,h1)
    READB2(pB[0], bH, 2);
    stageA(t1, 1);
    bar();
    MMAQ(0, 2, bH);
    // P3: aHi (no stage: dbuf0-B read at P2, stage must wait until P4)
    READA4(pA[0], 4);
    bar();
    MMAQ(4, 0, bL);
    // P4: stage B(t0+2) both halves [dbuf0-B last read P2 -> P4 = P2+2 OK];
    //     counted wait: drain t1 (A+B), leave B(t0+2)(4) in flight
    if (pf) { stageB(t0 + 2, 0); stageB(t0 + 2, 1);
              asm volatile("s_waitcnt vmcnt(4)"); }
    else    { asm volatile("s_waitcnt vmcnt(0)"); }
    bar();
    MMAQ(4, 2, bH);

    // ======== K-tile t1 (dbuf 1) ========
    // P5: aLo+bL ; stage A(t0+2,h0) [dbuf0-A last read P3 -> P5 = P3+2 OK]
    READA4(pA[1], 0);
    READB2(pB[1], bL, 0);
    if (pf) stageA(t0 + 2, 0);
    bar();
    MMAQ(0, 0, bL);
    // P6: bH ; stage A(t0+2,h1)
    READB2(pB[1], bH, 2);
    if (pf) stageA(t0 + 2, 1);
    bar();
    MMAQ(0, 2, bH);
    // P7: aHi (no stage: dbuf1-B read at P6, stage must wait until P8)
    READA4(pA[1], 4);
    bar();
    MMAQ(4, 0, bL);
    // P8: stage B(t1+2) both halves [dbuf1-B last read P6 -> P8 = P6+2 OK];
    //     counted wait: drain t0+2 (A+B), leave B(t1+2)(4) in flight
    if (pf) { stageB(t1 + 2, 0); stageB(t1 + 2, 1);
              asm volatile("s_waitcnt vmcnt(4)"); }
    else    { asm volatile("s_waitcnt vmcnt(0)"); }
    bar();
    MMAQ(4, 2, bH);
  }

  // ---- epilogue: C/D layout col=lane&15, row=(lane>>4)*4+reg ----
  const int m0 = mt * 256 + wr * 128;
  const int n0 = nt * 256 + wc * 64;
#pragma unroll
  for (int mi = 0; mi < 8; ++mi) {
#pragma unroll
    for (int ni = 0; ni < 4; ++ni) {
#pragma unroll
      for (int r = 0; r < 4; ++r) {
        const int row = m0 + mi * 16 + hi4 * 4 + r;
        const int col = n0 + ni * 16 + lr16;
        out[(size_t)row * N + col] = acc[mi][ni][r];
      }
    }
  }
}

// ---------------- legacy prep_x (fallback path) ------------------------------
__global__ __launch_bounds__(320)
void prep_x(const float* __restrict__ x, unsigned short* __restrict__ xt, int K) {
  const int kt = blockIdx.x, mt = blockIdx.y;
  unsigned short* tile = xt + (size_t)(mt * (K / 32) + kt) * (TILE_BYTES / 2);
#pragma unroll
  for (int p = 0; p < 2; ++p) {
    const int c = threadIdx.x + p * 320;
    const int r = c / 5, j = c - r * 5;
    uint4 o = {0u, 0u, 0u, 0u};
    if (j < 4) {
      const float* src = x + (size_t)(mt * 128 + r) * K + kt * 32 + j * 8;
      const float4 v0 = ((const float4*)src)[0];
      const float4 v1 = ((const float4*)src)[1];
      o.x = pkrtz_u32(v0.x, v0.y); o.y = pkrtz_u32(v0.z, v0.w);
      o.z = pkrtz_u32(v1.x, v1.y); o.w = pkrtz_u32(v1.z, v1.w);
    }
    *(uint4*)((char*)tile + (size_t)c * 16) = o;
  }
}

// ---------------- fallback 1: round-4 (A DMA, B fused dequant) ----------------
__global__ __launch_bounds__(512, 4)
void qgemm_dma(const unsigned short* __restrict__ xt,
               const unsigned* __restrict__ qweight,
               const unsigned* __restrict__ qzeros,
               const float* __restrict__ scales,
               float* __restrict__ out, int M, int N, int K) {
  __shared__ __align__(16) short As[128][LDK];
  __shared__ __align__(16) short Bs[256][LDK];

  const int tid = threadIdx.x;
  const int lane = tid & 63;
  const int wid = tid >> 6;
  const int n0 = blockIdx.x * 256;
  const int m0 = blockIdx.y * 128;
  const int mt = blockIdx.y;
  const int wm = (wid >> 2) * 64;
  const int wn = (wid & 3) * 64;
  const int lr = lane & 15;
  const int lk = (lane >> 4) * 8;

  const int b_n = tid & 255;
  const int b_kr0 = tid >> 8;
  const int gn = n0 + b_n;
  const unsigned* qwb = qweight + (size_t)b_kr0 * N + gn;

  const char* xt_b = (const char*)xt;
  const int NT = K / BK;

  v4f acc[4][4] = {};

  unsigned b0c, b1c, zpc;
  float scc;
  auto load_b = [&](int t, unsigned& b0, unsigned& b1, unsigned& zp, float& sc) {
    const int kk = t * BK;
    const size_t qoff = (size_t)(kk >> 3) * N;
    b0 = qwb[qoff];
    b1 = qwb[qoff + 2 * (size_t)N];
    const int g = kk >> 7;
    zp = qzeros[(size_t)g * (N >> 3) + (gn >> 3)];
    sc = scales[(size_t)g * N + gn];
  };
  load_b(0, b0c, b1c, zpc, scc);

#pragma unroll 2
  for (int t = 0; t < NT; ++t) {
    {
      const char* g = xt_b + (size_t)(mt * NT + t) * TILE_BYTES +
                      (size_t)wid * 1024 + (size_t)lane * 16;
      char* l = ((char*)&As[0][0]) + wid * 1024;
      load_lds_16B(g, l);
      if (wid < 2) load_lds_16B(g + 8 * 1024, l + 8 * 1024);
    }
    {
      const unsigned z = (zpc >> ((gn & 7) * 4)) & 15u;
      const unsigned hz_u = 0x64006400u | z | (z << 16);
      const half2v hz2 = __builtin_bit_cast(half2v, hz_u);
      const half2v hs2 = __builtin_bit_cast(half2v, pkrtz_u32(scc, scc));
      const unsigned qvs[2] = {b0c, b1c};
#pragma unroll
      for (int q = 0; q < 2; ++q) {
        const int kr = b_kr0 + q * 2;
        const unsigned qv = qvs[q];
        uint4 wv;
        unsigned* wp = (unsigned*)&wv;
#pragma unroll
        for (int j = 0; j < 4; ++j) {
          const unsigned byte = qv >> (8 * j);
          const unsigned pq = 0x64006400u | (byte & 0xFu) | ((byte & 0xF0u) << 12);
          const half2v w2 = (__builtin_bit_cast(half2v, pq) - hz2) * hs2;
          wp[j] = __builtin_bit_cast(unsigned, w2);
        }
        *(uint4*)(&Bs[b_n][kr * 8]) = wv;
      }
    }

    __syncthreads();

    unsigned b0n, b1n, zpn;
    float scn;
    const int tn = (t + 1 < NT) ? (t + 1) : t;
    load_b(tn, b0n, b1n, zpn, scn);

    v8h af[4], bfr[4];
#pragma unroll
    for (int i = 0; i < 4; ++i) {
      af[i] = *(const v8h*)(&As[wm + i * 16 + lr][lk]);
      bfr[i] = *(const v8h*)(&Bs[wn + i * 16 + lr][lk]);
    }
#pragma unroll
    for (int mi = 0; mi < 4; ++mi) {
#pragma unroll
      for (int ni = 0; ni < 4; ++ni) {
        acc[mi][ni] = __builtin_amdgcn_mfma_f32_16x16x32_f16(
            af[mi], bfr[ni], acc[mi][ni], 0, 0, 0);
      }
    }

    __syncthreads();

    b0c = b0n; b1c = b1n; zpc = zpn; scc = scn;
  }

#pragma unroll
  for (int mi = 0; mi < 4; ++mi) {
#pragma unroll
    for (int ni = 0; ni < 4; ++ni) {
#pragma unroll
      for (int r = 0; r < 4; ++r) {
        const int row = m0 + wm + mi * 16 + (lane >> 4) * 4 + r;
        const int col = n0 + wn + ni * 16 + lr;
        out[(size_t)row * N + col] = acc[mi][ni][r];
      }
    }
  }
}

// ---------------- fallback 2: round-3 fully fused (128x128) ----------------
__global__ __launch_bounds__(256, 2)
void qgemm_fused(const float* __restrict__ x,
                 const unsigned* __restrict__ qweight,
                 const unsigned* __restrict__ qzeros,
                 const float* __restrict__ scales,
                 float* __restrict__ out, int M, int N, int K) {
  __shared__ short As[128][LDK];
  __shared__ short Bs[128][LDK];

  const int tid = threadIdx.x;
  const int lane = tid & 63;
  const int wid = tid >> 6;
  const int n0 = blockIdx.x * 128;
  const int m0 = blockIdx.y * 128;
  const int wm = (wid >> 1) * 64;
  const int wn = (wid & 1) * 64;
  const int lr = lane & 15;
  const int lk = (lane >> 4) * 8;

  const int a_row = tid >> 3;
  const int a_col = (tid & 7) * 4;
  const int b_n = tid & 127;
  const int b_kr0 = tid >> 7;
  const int gn = n0 + b_n;

  const float* xb = x + (size_t)(m0 + a_row) * K + a_col;
  const unsigned* qwb = qweight + (size_t)b_kr0 * N + gn;

  v4f acc[4][4] = {};
  const int NT = K / BK;

  float4 axc[4];
  unsigned b0c, b1c, zpc;
  float scc;

  auto load_step = [&](int t, float4 ax[4], unsigned& b0, unsigned& b1,
                       unsigned& zp, float& sc) {
    const int kk = t * BK;
#pragma unroll
    for (int p = 0; p < 4; ++p)
      ax[p] = *(const float4*)(xb + (size_t)(p * 32) * K + kk);
    const size_t qoff = (size_t)(kk >> 3) * N;
    b0 = qwb[qoff];
    b1 = qwb[qoff + 2 * (size_t)N];
    const int g = kk >> 7;
    zp = qzeros[(size_t)g * (N >> 3) + (gn >> 3)];
    sc = scales[(size_t)g * N + gn];
  };

  load_step(0, axc, b0c, b1c, zpc, scc);

#pragma unroll 2
  for (int t = 0; t < NT; ++t) {
    const unsigned z = (zpc >> ((gn & 7) * 4)) & 15u;
    const unsigned hz_u = 0x64006400u | z | (z << 16);
    const half2v hz2 = __builtin_bit_cast(half2v, hz_u);
    const half2v hs2 = __builtin_bit_cast(half2v, pkrtz_u32(scc, scc));

#pragma unroll
    for (int p = 0; p < 4; ++p) {
      const int row = p * 32 + a_row;
      uint2 pv;
      pv.x = pkrtz_u32(axc[p].x, axc[p].y);
      pv.y = pkrtz_u32(axc[p].z, axc[p].w);
      *(uint2*)(&As[row][a_col]) = pv;
    }
    {
      const unsigned qvs[2] = {b0c, b1c};
#pragma unroll
      for (int q = 0; q < 2; ++q) {
        const int kr = b_kr0 + q * 2;
        const unsigned qv = qvs[q];
        uint4 wv;
        unsigned* wp = (unsigned*)&wv;
#pragma unroll
        for (int j = 0; j < 4; ++j) {
          const unsigned byte = qv >> (8 * j);
          const unsigned pq = 0x64006400u | (byte & 0xFu) | ((byte & 0xF0u) << 12);
          const half2v w2 = (__builtin_bit_cast(half2v, pq) - hz2) * hs2;
          wp[j] = __builtin_bit_cast(unsigned, w2);
        }
        *(uint4*)(&Bs[b_n][kr * 8]) = wv;
      }
    }

    __syncthreads();

    float4 axn[4];
    unsigned b0n, b1n, zpn;
    float scn;
    const int tn = (t + 1 < NT) ? (t + 1) : t;
    load_step(tn, axn, b0n, b1n, zpn, scn);

    v8h af[4], bfr[4];
#pragma unroll
    for (int i = 0; i < 4; ++i) {
      af[i] = *(const v8h*)(&As[wm + i * 16 + lr][lk]);
      bfr[i] = *(const v8h*)(&Bs[wn + i * 16 + lr][lk]);
    }
#pragma unroll
    for (int mi = 0; mi < 4; ++mi) {
#pragma unroll
      for (int ni = 0; ni < 4; ++ni) {
        acc[mi][ni] = __builtin_amdgcn_mfma_f32_16x16x32_f16(
            af[mi], bfr[ni], acc[mi][ni], 0, 0, 0);
      }
    }

    __syncthreads();

#pragma unroll
    for (int p = 0; p < 4; ++p) axc[p] = axn[p];
    b0c = b0n; b1c = b1n; zpc = zpn; scc = scn;
  }

#pragma unroll
  for (int mi = 0; mi < 4; ++mi) {
#pragma unroll
    for (int ni = 0; ni < 4; ++ni) {
#pragma unroll
      for (int r = 0; r < 4; ++r) {
        const int row = m0 + wm + mi * 16 + (lane >> 4) * 4 + r;
        const int col = n0 + wn + ni * 16 + lr;
        out[(size_t)row * N + col] = acc[mi][ni][r];
      }
    }
  }
}

extern "C" void kernel_launch(void* const* d_in, const int* in_sizes, int n_in,
                              void* d_out, int out_size, void* d_ws, size_t ws_size,
                              hipStream_t stream) {
  const float* x = (const float*)d_in[0];
  const unsigned* qweight = (const unsigned*)d_in[1];
  const unsigned* qzeros = (const unsigned*)d_in[2];
  const float* scales = (const float*)d_in[3];
  float* out = (float*)d_out;

  const int K = 4096;
  const int N = 11008;
  const int M = in_sizes[0] / K;  // 4096

  const size_t A8 = (size_t)(M / 256) * (K / 64) * 32768;  // 33.6 MB
  const size_t B8 = (size_t)(N / 256) * (K / 64) * 32768;  // 90.2 MB
  const size_t A_BYTES = (size_t)(M / 128) * (K / 32) * TILE_BYTES;  // legacy

  if ((M % 256 == 0) && ws_size >= A8 + B8) {
    unsigned short* fa = (unsigned short*)d_ws;
    unsigned short* fb = (unsigned short*)((char*)d_ws + A8);
    const int nblk = (M / 256) * (K / 64) + (N / 256) * (K / 64);
    prep_ab<<<dim3(nblk), 512, 0, stream>>>(x, qweight, qzeros, scales, fa, fb, M, N, K);
    qgemm8<<<dim3((M / 256) * (N / 256)), 512, 0, stream>>>(fa, fb, out, M, N, K);
  } else if (ws_size >= A_BYTES) {
    unsigned short* xt = (unsigned short*)d_ws;
    prep_x<<<dim3(K / 32, M / 128), 320, 0, stream>>>(x, xt, K);
    qgemm_dma<<<dim3(N / 256, M / 128), 512, 0, stream>>>(xt, qweight, qzeros, scales,
                                                          out, M, N, K);
  } else {
    qgemm_fused<<<dim3(N / 128, M / 128), 256, 0, stream>>>(x, qweight, qzeros, scales,
                                                            out, M, N, K);
  }
}

// Round 4
// 560.760 us; speedup vs baseline: 1.2211x; 1.0473x over previous
//
#include <hip/hip_runtime.h>

// QuantLinear W4A32 — round 10: round-9 + addressing/ILP polish in qgemm8.
//  * qgemm8 changes ONLY:
//    - 8 precomputed LDS read-base pointers (dbuf x kslot for A,B): every
//      ds_read_b128 is base + compile-time immediate offset (kills VALU addr calc).
//    - MMAQ k-slot outer loop: 8 independent MFMAs between accumulator reuses.
//    Schedule, windows, vmcnt ledger, layouts: identical to verified round-9.
//  * prep_ab: merged A/B prep, pre-swizzled (slot ^= row&7), unchanged.
// Fallbacks by ws_size: round-4 A-DMA path, then round-3 fully-fused path.

#define BK 32
#define LDK 40             // legacy padded row stride (fallback path)
#define TILE_BYTES 10240   // legacy A tile

typedef _Float16 v8h __attribute__((ext_vector_type(8)));
typedef _Float16 half2v __attribute__((ext_vector_type(2)));
typedef float v4f __attribute__((ext_vector_type(4)));

__device__ __forceinline__ unsigned pkrtz_u32(float a, float b) {
  return __builtin_bit_cast(unsigned, __builtin_amdgcn_cvt_pkrtz(a, b));
}

__device__ __forceinline__ void load_lds_16B(const void* g, void* l) {
  __builtin_amdgcn_global_load_lds(
      (const __attribute__((address_space(1))) unsigned*)g,
      (__attribute__((address_space(3))) unsigned*)l, 16, 0, 0);
}

__device__ __forceinline__ void bar() { asm volatile("s_barrier" ::: "memory"); }

// ---------------- prep_ab: merged operand prep (unchanged) -------------------
__global__ __launch_bounds__(512)
void prep_ab(const float* __restrict__ x,
             const unsigned* __restrict__ qweight,
             const unsigned* __restrict__ qzeros,
             const float* __restrict__ scales,
             unsigned short* __restrict__ fa,
             unsigned short* __restrict__ fb, int M, int N, int K) {
  const int KT = K / 64;
  const int NA = (M / 256) * KT;
  int b = blockIdx.x;
  if (b < NA) {
    const int mt = b / KT, t = b - mt * KT;
    unsigned short* tile = fa + (size_t)(mt * KT + t) * 16384;
#pragma unroll
    for (int p = 0; p < 4; ++p) {
      const int c = threadIdx.x + p * 512;
      const int h = c >> 10, r = (c >> 3) & 127, s = c & 7;
      const float* src = x + (size_t)(mt * 256 + h * 128 + r) * K + t * 64 + s * 8;
      const float4 v0 = ((const float4*)src)[0];
      const float4 v1 = ((const float4*)src)[1];
      uint4 o;
      o.x = pkrtz_u32(v0.x, v0.y); o.y = pkrtz_u32(v0.z, v0.w);
      o.z = pkrtz_u32(v1.x, v1.y); o.w = pkrtz_u32(v1.z, v1.w);
      *(uint4*)(tile + h * 8192 + r * 64 + ((s ^ (r & 7)) << 3)) = o;
    }
  } else {
    b -= NA;
    const int nt = b / KT, t = b - nt * KT;
    const int g = t >> 1;  // GROUP=128 = 2 K-tiles
    unsigned short* tile = fb + (size_t)(nt * KT + t) * 16384;
#pragma unroll
    for (int p = 0; p < 4; ++p) {
      const int c = threadIdx.x + p * 512;
      const int h = c >> 10, r = (c >> 3) & 127, s = c & 7;
      const int n = nt * 256 + h * 128 + r;
      const unsigned zp = qzeros[(size_t)g * (N >> 3) + (n >> 3)];
      const float sc = scales[(size_t)g * N + n];
      const unsigned z = (zp >> ((n & 7) * 4)) & 15u;
      const unsigned hz_u = 0x64006400u | z | (z << 16);
      const half2v hz2 = __builtin_bit_cast(half2v, hz_u);
      const half2v hs2 = __builtin_bit_cast(half2v, pkrtz_u32(sc, sc));
      const unsigned qv = qweight[(size_t)(t * 8 + s) * N + n];
      uint4 o;
      unsigned* wp = (unsigned*)&o;
#pragma unroll
      for (int bb = 0; bb < 4; ++bb) {
        const unsigned byte = qv >> (8 * bb);
        const unsigned pq = 0x64006400u | (byte & 0xFu) | ((byte & 0xF0u) << 12);
        const half2v w2 = (__builtin_bit_cast(half2v, pq) - hz2) * hs2;
        wp[bb] = __builtin_bit_cast(unsigned, w2);
      }
      *(uint4*)(tile + h * 8192 + r * 64 + ((s ^ (r & 7)) << 3)) = o;
    }
  }
}

// ---------------- main: 8-phase 256x256 pipelined GEMM, 1 bar/phase ----------
// All ds_reads use precomputed per-(dbuf,kslot) bases + immediate offsets.

#define READA4(D, MB)                                                          \
  _Pragma("unroll") for (int i = 0; i < 4; ++i) {                              \
    aF[i][0] = *(const v8h*)(rdA##D##0 + (MB + i) * 2048);                     \
    aF[i][1] = *(const v8h*)(rdA##D##1 + (MB + i) * 2048);                     \
  }

#define READB2(D, BF, NB)                                                      \
  _Pragma("unroll") for (int j = 0; j < 2; ++j) {                              \
    BF[j][0] = *(const v8h*)(rdB##D##0 + (NB + j) * 2048);                     \
    BF[j][1] = *(const v8h*)(rdB##D##1 + (NB + j) * 2048);                     \
  }

// k-slot OUTER: 8 independent MFMAs before any accumulator reuse.
#define MMAQ(MB, NB, BF)                                                       \
  __builtin_amdgcn_s_setprio(1);                                               \
  _Pragma("unroll") for (int s = 0; s < 2; ++s)                                \
  _Pragma("unroll") for (int i = 0; i < 4; ++i)                                \
  _Pragma("unroll") for (int j = 0; j < 2; ++j) {                              \
    acc[MB + i][NB + j] = __builtin_amdgcn_mfma_f32_16x16x32_f16(              \
        aF[i][s], BF[j][s], acc[MB + i][NB + j], 0, 0, 0);                     \
  }                                                                            \
  __builtin_amdgcn_s_setprio(0);

__global__ __launch_bounds__(512, 2)
void qgemm8(const unsigned short* __restrict__ fa,
            const unsigned short* __restrict__ fb,
            float* __restrict__ out, int M, int N, int K) {
  // [dbuf][half 128 rows][row][k] : 2*2*128*64*2B = 64KB each operand
  __shared__ __align__(16) short As[2][2][128][64];
  __shared__ __align__(16) short Bs[2][2][128][64];

  const int tid = threadIdx.x;
  const int lane = tid & 63;
  const int wid = tid >> 6;  // 8 waves: (wr 0..1) x (wc 0..3)
  const int wr = wid >> 2, wc = wid & 3;
  const int lr16 = lane & 15, hi4 = lane >> 4, l7 = lane & 7;
  const int koff0 = ((hi4 ^ l7) << 4);        // ks=0 slot
  const int koff1 = (((4 + hi4) ^ l7) << 4);  // ks=1 slot

  const int nmt = M / 256;            // 16
  const int nwg = nmt * (N / 256);    // 688 (divisible by 8)
  int bid = blockIdx.x;
  {
    const int xcd = bid & 7, idx = bid >> 3;
    const int q = nwg >> 3, r = nwg & 7;
    bid = (xcd < r ? xcd * (q + 1) : r * (q + 1) + (xcd - r) * q) + idx;
  }
  const int mt = bid % nmt;  // m fastest -> W panel L2-resident per XCD
  const int nt = bid / nmt;

  const int NT = K / 64;    // 64 K-tiles
  const int NI = NT / 2;    // 32 iterations (2 K-tiles each)

  const char* srcA = (const char*)fa + (size_t)mt * NT * 32768 + wid * 1024 + lane * 16;
  const char* srcB = (const char*)fb + (size_t)nt * NT * 32768 + wid * 1024 + lane * 16;
  char* ldsA = (char*)&As[0][0][0][0];
  char* ldsB = (char*)&Bs[0][0][0][0];
  char* dstA = ldsA + wid * 1024;  // HW appends lane*16
  char* dstB = ldsB + wid * 1024;

  auto stageA = [&](int T, int h) {
    const char* s = srcA + (size_t)T * 32768 + h * 16384;
    char* d = dstA + (T & 1) * 32768 + h * 16384;
    load_lds_16B(s, d);
    load_lds_16B(s + 8192, d + 8192);
  };
  auto stageB = [&](int T, int h) {
    const char* s = srcB + (size_t)T * 32768 + h * 16384;
    char* d = dstB + (T & 1) * 32768 + h * 16384;
    load_lds_16B(s, d);
    load_lds_16B(s + 8192, d + 8192);
  };

  // Precomputed ds_read bases: base = operand + dbuf + wave-half + lane row/slot.
  const char* rdA00 = ldsA + wr * 16384 + lr16 * 128 + koff0;
  const char* rdA01 = ldsA + wr * 16384 + lr16 * 128 + koff1;
  const char* rdA10 = rdA00 + 32768;
  const char* rdA11 = rdA01 + 32768;
  const char* rdB00 = ldsB + (wc >> 1) * 16384 + (wc & 1) * 8192 + lr16 * 128 + koff0;
  const char* rdB01 = ldsB + (wc >> 1) * 16384 + (wc & 1) * 8192 + lr16 * 128 + koff1;
  const char* rdB10 = rdB00 + 32768;
  const char* rdB11 = rdB01 + 32768;

  v4f acc[8][4] = {};
  v8h aF[4][2], bL[2][2], bH[2][2];

  // ---- prologue: t0 {B0,B1,A0,A1}, t1 {B0,B1}; wait t0 landed (t1-B in flight)
  stageB(0, 0); stageB(0, 1); stageA(0, 0); stageA(0, 1);
  stageB(1, 0); stageB(1, 1);
  asm volatile("s_waitcnt vmcnt(4)");
  bar();

  for (int it = 0; it < NI; ++it) {
    const int t0 = 2 * it, t1 = 2 * it + 1;
    const bool pf = (it < NI - 1);

    // ======== K-tile t0 (dbuf 0) ========
    // P1: aLo+bL ; stage A(t1,h0) [dbuf1-A last read prev P7 -> P1 = P7+2 OK]
    READA4(0, 0);
    READB2(0, bL, 0);
    stageA(t1, 0);
    bar();
    MMAQ(0, 0, bL);
    // P2: bH ; stage A(t1,h1)
    READB2(0, bH, 2);
    stageA(t1, 1);
    bar();
    MMAQ(0, 2, bH);
    // P3: aHi (no stage: dbuf0-B read at P2, stage must wait until P4)
    READA4(0, 4);
    bar();
    MMAQ(4, 0, bL);
    // P4: stage B(t0+2) both halves [dbuf0-B last read P2 -> P4 = P2+2 OK];
    //     counted wait: drain t1 (A+B), leave B(t0+2)(4) in flight
    if (pf) { stageB(t0 + 2, 0); stageB(t0 + 2, 1);
              asm volatile("s_waitcnt vmcnt(4)"); }
    else    { asm volatile("s_waitcnt vmcnt(0)"); }
    bar();
    MMAQ(4, 2, bH);

    // ======== K-tile t1 (dbuf 1) ========
    // P5: aLo+bL ; stage A(t0+2,h0) [dbuf0-A last read P3 -> P5 = P3+2 OK]
    READA4(1, 0);
    READB2(1, bL, 0);
    if (pf) stageA(t0 + 2, 0);
    bar();
    MMAQ(0, 0, bL);
    // P6: bH ; stage A(t0+2,h1)
    READB2(1, bH, 2);
    if (pf) stageA(t0 + 2, 1);
    bar();
    MMAQ(0, 2, bH);
    // P7: aHi (no stage: dbuf1-B read at P6, stage must wait until P8)
    READA4(1, 4);
    bar();
    MMAQ(4, 0, bL);
    // P8: stage B(t1+2) both halves [dbuf1-B last read P6 -> P8 = P6+2 OK];
    //     counted wait: drain t0+2 (A+B), leave B(t1+2)(4) in flight
    if (pf) { stageB(t1 + 2, 0); stageB(t1 + 2, 1);
              asm volatile("s_waitcnt vmcnt(4)"); }
    else    { asm volatile("s_waitcnt vmcnt(0)"); }
    bar();
    MMAQ(4, 2, bH);
  }

  // ---- epilogue: C/D layout col=lane&15, row=(lane>>4)*4+reg ----
  const int m0 = mt * 256 + wr * 128;
  const int n0 = nt * 256 + wc * 64;
  float* obase = out + (size_t)(m0 + hi4 * 4) * N + n0 + lr16;
#pragma unroll
  for (int mi = 0; mi < 8; ++mi) {
#pragma unroll
    for (int ni = 0; ni < 4; ++ni) {
#pragma unroll
      for (int r = 0; r < 4; ++r) {
        obase[(size_t)(mi * 16 + r) * N + ni * 16] = acc[mi][ni][r];
      }
    }
  }
}

// ---------------- legacy prep_x (fallback path) ------------------------------
__global__ __launch_bounds__(320)
void prep_x(const float* __restrict__ x, unsigned short* __restrict__ xt, int K) {
  const int kt = blockIdx.x, mt = blockIdx.y;
  unsigned short* tile = xt + (size_t)(mt * (K / 32) + kt) * (TILE_BYTES / 2);
#pragma unroll
  for (int p = 0; p < 2; ++p) {
    const int c = threadIdx.x + p * 320;
    const int r = c / 5, j = c - r * 5;
    uint4 o = {0u, 0u, 0u, 0u};
    if (j < 4) {
      const float* src = x + (size_t)(mt * 128 + r) * K + kt * 32 + j * 8;
      const float4 v0 = ((const float4*)src)[0];
      const float4 v1 = ((const float4*)src)[1];
      o.x = pkrtz_u32(v0.x, v0.y); o.y = pkrtz_u32(v0.z, v0.w);
      o.z = pkrtz_u32(v1.x, v1.y); o.w = pkrtz_u32(v1.z, v1.w);
    }
    *(uint4*)((char*)tile + (size_t)c * 16) = o;
  }
}

// ---------------- fallback 1: round-4 (A DMA, B fused dequant) ----------------
__global__ __launch_bounds__(512, 4)
void qgemm_dma(const unsigned short* __restrict__ xt,
               const unsigned* __restrict__ qweight,
               const unsigned* __restrict__ qzeros,
               const float* __restrict__ scales,
               float* __restrict__ out, int M, int N, int K) {
  __shared__ __align__(16) short As[128][LDK];
  __shared__ __align__(16) short Bs[256][LDK];

  const int tid = threadIdx.x;
  const int lane = tid & 63;
  const int wid = tid >> 6;
  const int n0 = blockIdx.x * 256;
  const int m0 = blockIdx.y * 128;
  const int mt = blockIdx.y;
  const int wm = (wid >> 2) * 64;
  const int wn = (wid & 3) * 64;
  const int lr = lane & 15;
  const int lk = (lane >> 4) * 8;

  const int b_n = tid & 255;
  const int b_kr0 = tid >> 8;
  const int gn = n0 + b_n;
  const unsigned* qwb = qweight + (size_t)b_kr0 * N + gn;

  const char* xt_b = (const char*)xt;
  const int NT = K / BK;

  v4f acc[4][4] = {};

  unsigned b0c, b1c, zpc;
  float scc;
  auto load_b = [&](int t, unsigned& b0, unsigned& b1, unsigned& zp, float& sc) {
    const int kk = t * BK;
    const size_t qoff = (size_t)(kk >> 3) * N;
    b0 = qwb[qoff];
    b1 = qwb[qoff + 2 * (size_t)N];
    const int g = kk >> 7;
    zp = qzeros[(size_t)g * (N >> 3) + (gn >> 3)];
    sc = scales[(size_t)g * N + gn];
  };
  load_b(0, b0c, b1c, zpc, scc);

#pragma unroll 2
  for (int t = 0; t < NT; ++t) {
    {
      const char* g = xt_b + (size_t)(mt * NT + t) * TILE_BYTES +
                      (size_t)wid * 1024 + (size_t)lane * 16;
      char* l = ((char*)&As[0][0]) + wid * 1024;
      load_lds_16B(g, l);
      if (wid < 2) load_lds_16B(g + 8 * 1024, l + 8 * 1024);
    }
    {
      const unsigned z = (zpc >> ((gn & 7) * 4)) & 15u;
      const unsigned hz_u = 0x64006400u | z | (z << 16);
      const half2v hz2 = __builtin_bit_cast(half2v, hz_u);
      const half2v hs2 = __builtin_bit_cast(half2v, pkrtz_u32(scc, scc));
      const unsigned qvs[2] = {b0c, b1c};
#pragma unroll
      for (int q = 0; q < 2; ++q) {
        const int kr = b_kr0 + q * 2;
        const unsigned qv = qvs[q];
        uint4 wv;
        unsigned* wp = (unsigned*)&wv;
#pragma unroll
        for (int j = 0; j < 4; ++j) {
          const unsigned byte = qv >> (8 * j);
          const unsigned pq = 0x64006400u | (byte & 0xFu) | ((byte & 0xF0u) << 12);
          const half2v w2 = (__builtin_bit_cast(half2v, pq) - hz2) * hs2;
          wp[j] = __builtin_bit_cast(unsigned, w2);
        }
        *(uint4*)(&Bs[b_n][kr * 8]) = wv;
      }
    }

    __syncthreads();

    unsigned b0n, b1n, zpn;
    float scn;
    const int tn = (t + 1 < NT) ? (t + 1) : t;
    load_b(tn, b0n, b1n, zpn, scn);

    v8h af[4], bfr[4];
#pragma unroll
    for (int i = 0; i < 4; ++i) {
      af[i] = *(const v8h*)(&As[wm + i * 16 + lr][lk]);
      bfr[i] = *(const v8h*)(&Bs[wn + i * 16 + lr][lk]);
    }
#pragma unroll
    for (int mi = 0; mi < 4; ++mi) {
#pragma unroll
      for (int ni = 0; ni < 4; ++ni) {
        acc[mi][ni] = __builtin_amdgcn_mfma_f32_16x16x32_f16(
            af[mi], bfr[ni], acc[mi][ni], 0, 0, 0);
      }
    }

    __syncthreads();

    b0c = b0n; b1c = b1n; zpc = zpn; scc = scn;
  }

#pragma unroll
  for (int mi = 0; mi < 4; ++mi) {
#pragma unroll
    for (int ni = 0; ni < 4; ++ni) {
#pragma unroll
      for (int r = 0; r < 4; ++r) {
        const int row = m0 + wm + mi * 16 + (lane >> 4) * 4 + r;
        const int col = n0 + wn + ni * 16 + lr;
        out[(size_t)row * N + col] = acc[mi][ni][r];
      }
    }
  }
}

// ---------------- fallback 2: round-3 fully fused (128x128) ----------------
__global__ __launch_bounds__(256, 2)
void qgemm_fused(const float* __restrict__ x,
                 const unsigned* __restrict__ qweight,
                 const unsigned* __restrict__ qzeros,
                 const float* __restrict__ scales,
                 float* __restrict__ out, int M, int N, int K) {
  __shared__ short As[128][LDK];
  __shared__ short Bs[128][LDK];

  const int tid = threadIdx.x;
  const int lane = tid & 63;
  const int wid = tid >> 6;
  const int n0 = blockIdx.x * 128;
  const int m0 = blockIdx.y * 128;
  const int wm = (wid >> 1) * 64;
  const int wn = (wid & 1) * 64;
  const int lr = lane & 15;
  const int lk = (lane >> 4) * 8;

  const int a_row = tid >> 3;
  const int a_col = (tid & 7) * 4;
  const int b_n = tid & 127;
  const int b_kr0 = tid >> 7;
  const int gn = n0 + b_n;

  const float* xb = x + (size_t)(m0 + a_row) * K + a_col;
  const unsigned* qwb = qweight + (size_t)b_kr0 * N + gn;

  v4f acc[4][4] = {};
  const int NT = K / BK;

  float4 axc[4];
  unsigned b0c, b1c, zpc;
  float scc;

  auto load_step = [&](int t, float4 ax[4], unsigned& b0, unsigned& b1,
                       unsigned& zp, float& sc) {
    const int kk = t * BK;
#pragma unroll
    for (int p = 0; p < 4; ++p)
      ax[p] = *(const float4*)(xb + (size_t)(p * 32) * K + kk);
    const size_t qoff = (size_t)(kk >> 3) * N;
    b0 = qwb[qoff];
    b1 = qwb[qoff + 2 * (size_t)N];
    const int g = kk >> 7;
    zp = qzeros[(size_t)g * (N >> 3) + (gn >> 3)];
    sc = scales[(size_t)g * N + gn];
  };

  load_step(0, axc, b0c, b1c, zpc, scc);

#pragma unroll 2
  for (int t = 0; t < NT; ++t) {
    const unsigned z = (zpc >> ((gn & 7) * 4)) & 15u;
    const unsigned hz_u = 0x64006400u | z | (z << 16);
    const half2v hz2 = __builtin_bit_cast(half2v, hz_u);
    const half2v hs2 = __builtin_bit_cast(half2v, pkrtz_u32(scc, scc));

#pragma unroll
    for (int p = 0; p < 4; ++p) {
      const int row = p * 32 + a_row;
      uint2 pv;
      pv.x = pkrtz_u32(axc[p].x, axc[p].y);
      pv.y = pkrtz_u32(axc[p].z, axc[p].w);
      *(uint2*)(&As[row][a_col]) = pv;
    }
    {
      const unsigned qvs[2] = {b0c, b1c};
#pragma unroll
      for (int q = 0; q < 2; ++q) {
        const int kr = b_kr0 + q * 2;
        const unsigned qv = qvs[q];
        uint4 wv;
        unsigned* wp = (unsigned*)&wv;
#pragma unroll
        for (int j = 0; j < 4; ++j) {
          const unsigned byte = qv >> (8 * j);
          const unsigned pq = 0x64006400u | (byte & 0xFu) | ((byte & 0xF0u) << 12);
          const half2v w2 = (__builtin_bit_cast(half2v, pq) - hz2) * hs2;
          wp[j] = __builtin_bit_cast(unsigned, w2);
        }
        *(uint4*)(&Bs[b_n][kr * 8]) = wv;
      }
    }

    __syncthreads();

    float4 axn[4];
    unsigned b0n, b1n, zpn;
    float scn;
    const int tn = (t + 1 < NT) ? (t + 1) : t;
    load_step(tn, axn, b0n, b1n, zpn, scn);

    v8h af[4], bfr[4];
#pragma unroll
    for (int i = 0; i < 4; ++i) {
      af[i] = *(const v8h*)(&As[wm + i * 16 + lr][lk]);
      bfr[i] = *(const v8h*)(&Bs[wn + i * 16 + lr][lk]);
    }
#pragma unroll
    for (int mi = 0; mi < 4; ++mi) {
#pragma unroll
      for (int ni = 0; ni < 4; ++ni) {
        acc[mi][ni] = __builtin_amdgcn_mfma_f32_16x16x32_f16(
            af[mi], bfr[ni], acc[mi][ni], 0, 0, 0);
      }
    }

    __syncthreads();

#pragma unroll
    for (int p = 0; p < 4; ++p) axc[p] = axn[p];
    b0c = b0n; b1c = b1n; zpc = zpn; scc = scn;
  }

#pragma unroll
  for (int mi = 0; mi < 4; ++mi) {
#pragma unroll
    for (int ni = 0; ni < 4; ++ni) {
#pragma unroll
      for (int r = 0; r < 4; ++r) {
        const int row = m0 + wm + mi * 16 + (lane >> 4) * 4 + r;
        const int col = n0 + wn + ni * 16 + lr;
        out[(size_t)row * N + col] = acc[mi][ni][r];
      }
    }
  }
}

extern "C" void kernel_launch(void* const* d_in, const int* in_sizes, int n_in,
                              void* d_out, int out_size, void* d_ws, size_t ws_size,
                              hipStream_t stream) {
  const float* x = (const float*)d_in[0];
  const unsigned* qweight = (const unsigned*)d_in[1];
  const unsigned* qzeros = (const unsigned*)d_in[2];
  const float* scales = (const float*)d_in[3];
  float* out = (float*)d_out;

  const int K = 4096;
  const int N = 11008;
  const int M = in_sizes[0] / K;  // 4096

  const size_t A8 = (size_t)(M / 256) * (K / 64) * 32768;  // 33.6 MB
  const size_t B8 = (size_t)(N / 256) * (K / 64) * 32768;  // 90.2 MB
  const size_t A_BYTES = (size_t)(M / 128) * (K / 32) * TILE_BYTES;  // legacy

  if ((M % 256 == 0) && ws_size >= A8 + B8) {
    unsigned short* fa = (unsigned short*)d_ws;
    unsigned short* fb = (unsigned short*)((char*)d_ws + A8);
    const int nblk = (M / 256) * (K / 64) + (N / 256) * (K / 64);
    prep_ab<<<dim3(nblk), 512, 0, stream>>>(x, qweight, qzeros, scales, fa, fb, M, N, K);
    qgemm8<<<dim3((M / 256) * (N / 256)), 512, 0, stream>>>(fa, fb, out, M, N, K);
  } else if (ws_size >= A_BYTES) {
    unsigned short* xt = (unsigned short*)d_ws;
    prep_x<<<dim3(K / 32, M / 128), 320, 0, stream>>>(x, xt, K);
    qgemm_dma<<<dim3(N / 256, M / 128), 512, 0, stream>>>(xt, qweight, qzeros, scales,
                                                          out, M, N, K);
  } else {
    qgemm_fused<<<dim3(N / 128, M / 128), 256, 0, stream>>>(x, qweight, qzeros, scales,
                                                            out, M, N, K);
  }
}